// Round 8
// baseline (400.086 us; speedup 1.0000x reference)
//
#include <hip/hip_runtime.h>
#include <hip/hip_bf16.h>
#include <stdint.h>

typedef __attribute__((ext_vector_type(8))) short short8;
typedef __attribute__((ext_vector_type(4))) float f32x4;

#define N_HEADS 12
#define HD      64
#define BSZ     8
#define TSZ     1024
#define CSZ     768
#define MSZ     (BSZ * TSZ)   /* 8192 */
#define N3      (3 * CSZ)     /* 2304 */
#define LDA     72            /* padded LDS stride for attn S-tile */

static __device__ __forceinline__ unsigned short f2bf(float f) {
    union { float f; uint32_t u; } v; v.f = f;
    uint32_t r = v.u + 0x7fffu + ((v.u >> 16) & 1u);
    return (unsigned short)(r >> 16);
}

// async global->LDS, 16B per lane, LDS dest = wave-uniform base + lane*16
static __device__ __forceinline__ void gload16f(const float* g, float* l) {
    __builtin_amdgcn_global_load_lds(
        (const __attribute__((address_space(1))) void*)g,
        (__attribute__((address_space(3))) void*)l, 16, 0, 0);
}

// pack 8 consecutive f32 (two float4) into a bf16x8 MFMA fragment (RNE)
static __device__ __forceinline__ short8 pack8(float4 a, float4 b) {
    union { short8 s; __hip_bfloat162 h[4]; } u;
    u.h[0] = __float22bfloat162_rn(make_float2(a.x, a.y));
    u.h[1] = __float22bfloat162_rn(make_float2(a.z, a.w));
    u.h[2] = __float22bfloat162_rn(make_float2(b.x, b.y));
    u.h[3] = __float22bfloat162_rn(make_float2(b.z, b.w));
    return u.s;
}

// ---------------- QKV projection GEMM (f32-direct staging) ----------------
// C[m][n] = sum_k x[m][k]*W[n][k] + b[n]. Stages x,W as f32 via
// global_load_lds (no separate cvt pass / no bf16 copy round trip);
// f32->bf16 conversion happens at ds_read time via packed cvt (cheap VALU).
// r5 structure otherwise: 128x128 tile, BK=64, 4 waves, 2 barriers/K-step.
__global__ __launch_bounds__(256, 2) void qkv_gemm(
    const float* __restrict__ x,    // [8192][768] f32
    const float* __restrict__ W,    // [2304][768] f32
    const float* __restrict__ bias, // [2304] f32
    unsigned short* __restrict__ qo,
    unsigned short* __restrict__ ko,
    unsigned short* __restrict__ vto)
{
    __shared__ float Af[128 * 64];
    __shared__ float Bf[128 * 64];
    const int tid = threadIdx.x;
    const int lane = tid & 63;
    const int w = tid >> 6;
    const int lr = lane >> 4, lc = lane & 15;
    const int m0 = blockIdx.y * 128;
    const int n0 = blockIdx.x * 128;
    const int wm = (w >> 1) * 64, wn = (w & 1) * 64;

    // staging: wave w stages rows [w*32, w*32+32); inst j covers 4 rows;
    // lane -> row j*4 + (lane>>4), f32 col (lane&15)*4 (16B per lane)
    const float* ga = x + (size_t)(m0 + w * 32 + (lane >> 4)) * CSZ + (lane & 15) * 4;
    const float* gb = W + (size_t)(n0 + w * 32 + (lane >> 4)) * CSZ + (lane & 15) * 4;
    float* la = Af + (w * 32) * 64;
    float* lb = Bf + (w * 32) * 64;

    f32x4 acc[4][4] = {};

    for (int kt = 0; kt < CSZ; kt += 64) {
        __syncthreads();
        #pragma unroll
        for (int j = 0; j < 8; ++j) {
            gload16f(ga + (size_t)j * 4 * CSZ + kt, la + j * 256);
            gload16f(gb + (size_t)j * 4 * CSZ + kt, lb + j * 256);
        }
        __syncthreads();
        #pragma unroll
        for (int ks = 0; ks < 2; ++ks) {
            short8 af[4], bf_[4];
            #pragma unroll
            for (int mi = 0; mi < 4; ++mi) {
                const float* p = Af + (wm + mi * 16 + lc) * 64 + ks * 32 + lr * 8;
                af[mi] = pack8(*reinterpret_cast<const float4*>(p),
                               *reinterpret_cast<const float4*>(p + 4));
            }
            #pragma unroll
            for (int ni = 0; ni < 4; ++ni) {
                const float* p = Bf + (wn + ni * 16 + lc) * 64 + ks * 32 + lr * 8;
                bf_[ni] = pack8(*reinterpret_cast<const float4*>(p),
                                *reinterpret_cast<const float4*>(p + 4));
            }
            #pragma unroll
            for (int mi = 0; mi < 4; ++mi)
                #pragma unroll
                for (int ni = 0; ni < 4; ++ni)
                    acc[mi][ni] = __builtin_amdgcn_mfma_f32_16x16x32_bf16(
                        af[mi], bf_[ni], acc[mi][ni], 0, 0, 0);
        }
    }

    // 768 is a multiple of 128, so the q/k/v section is uniform per block.
    const int sec = n0 / CSZ;
    const int nb = n0 - sec * CSZ;
    #pragma unroll
    for (int ni = 0; ni < 4; ++ni) {
        int ncol = wn + ni * 16 + lc;       // 0..127 within block
        int nn = nb + ncol;                 // 0..767 within section
        float badd = bias[n0 + ncol];
        int h = nn >> 6, d = nn & 63;
        #pragma unroll
        for (int mi = 0; mi < 4; ++mi) {
            #pragma unroll
            for (int r = 0; r < 4; ++r) {
                int m = m0 + wm + mi * 16 + lr * 4 + r;
                int bb = m >> 10, t = m & 1023;
                int plane = bb * N_HEADS + h;
                float v = acc[mi][ni][r] + badd;
                if (sec == 0)
                    qo[((size_t)plane * TSZ + t) * HD + d] = f2bf(v * 0.125f);
                else if (sec == 1)
                    ko[((size_t)plane * TSZ + t) * HD + d] = f2bf(v);
                else
                    vto[((size_t)plane * HD + d) * TSZ + t] = f2bf(v);
            }
        }
    }
}

// ---------------- causal-ReLU attention ----------------
// 32 query rows per wave (2x the wave count of the 64-row version ->
// 3 waves/SIMD, latency-bound chain needs the TLP). 2 waves per block,
// wave 0 -> q-tile j, wave 1 -> q-tile 31-j: every block runs exactly
// 17 kv-steps (balanced). Waves are independent (no __syncthreads).
// S^T = mfma(K_frag, Q_frag) -> mask+ReLU -> packed bf16 -> ds_write_b64
// -> PV from LDS S-frags and global v^T frags.
__global__ __launch_bounds__(128, 3) void attn_kernel(
    const unsigned short* __restrict__ q,    // [96][1024][64] bf16 (pre-scaled)
    const unsigned short* __restrict__ k,    // [96][1024][64] bf16
    const unsigned short* __restrict__ vt,   // [96][64][1024] bf16
    float* __restrict__ out)                 // [8][1024][768] f32
{
    __shared__ unsigned short smem[2 * 32 * LDA];
    const int wid = threadIdx.x >> 6;
    const int lane = threadIdx.x & 63;
    const int lr = lane >> 4, lc = lane & 15;
    const int qw = wid == 0 ? blockIdx.x : 31 - blockIdx.x;   // 0..31
    const int bh = blockIdx.y;               // 0..95
    const int b = bh / N_HEADS, h = bh - b * N_HEADS;
    const size_t base = (size_t)bh * (TSZ * HD);
    const int qrow0 = qw * 32;
    const int lastkt = qw >> 1;
    unsigned short* sm = smem + wid * 32 * LDA;

    // Q fragments (MFMA B operand for the S^T trick): 2 q-frags x 2 k-slices
    short8 aq[2][2];
    #pragma unroll
    for (int ks = 0; ks < 2; ++ks)
        #pragma unroll
        for (int qi = 0; qi < 2; ++qi)
            aq[ks][qi] = *reinterpret_cast<const short8*>(
                q + base + (size_t)(qrow0 + qi * 16 + lc) * HD + ks * 32 + lr * 8);

    f32x4 y[2][4] = {};

    for (int kt = 0; kt <= lastkt; ++kt) {
        const int kv0 = kt * 64;
        f32x4 st[4][2] = {};   // S^T fragments: rows kv (4x16), cols q (2x16)
        #pragma unroll
        for (int ks = 0; ks < 2; ++ks) {
            short8 ak[4];
            #pragma unroll
            for (int ki = 0; ki < 4; ++ki)
                ak[ki] = *reinterpret_cast<const short8*>(
                    k + base + (size_t)(kv0 + ki * 16 + lc) * HD + ks * 32 + lr * 8);
            #pragma unroll
            for (int ki = 0; ki < 4; ++ki)
                #pragma unroll
                for (int qi = 0; qi < 2; ++qi)
                    st[ki][qi] = __builtin_amdgcn_mfma_f32_16x16x32_bf16(
                        ak[ki], aq[ks][qi], st[ki][qi], 0, 0, 0);
        }
        const bool diag = (kt == lastkt);
        #pragma unroll
        for (int ki = 0; ki < 4; ++ki) {
            #pragma unroll
            for (int qi = 0; qi < 2; ++qi) {
                float vv[4];
                #pragma unroll
                for (int r = 0; r < 4; ++r) {
                    float s = fmaxf(st[ki][qi][r], 0.0f);          // ReLU
                    if (diag && (kv0 + ki * 16 + lr * 4 + r > qrow0 + qi * 16 + lc))
                        s = 0.0f;                                   // causal mask
                    vv[r] = s;
                }
                __hip_bfloat162 p0 = __float22bfloat162_rn(make_float2(vv[0], vv[1]));
                __hip_bfloat162 p1 = __float22bfloat162_rn(make_float2(vv[2], vv[3]));
                uint2 pk;
                pk.x = *reinterpret_cast<unsigned*>(&p0);
                pk.y = *reinterpret_cast<unsigned*>(&p1);
                // S[q][kv] layout: 4 consecutive kv per lane -> one b64 write
                *reinterpret_cast<uint2*>(
                    sm + (qi * 16 + lc) * LDA + ki * 16 + lr * 4) = pk;
            }
        }
        // PV: y[q][d] += S[q][kv] * V[kv][d]  (V via transposed vt[d][kv])
        #pragma unroll
        for (int ks = 0; ks < 2; ++ks) {
            short8 as[2], bv[4];
            #pragma unroll
            for (int qi = 0; qi < 2; ++qi)
                as[qi] = *reinterpret_cast<const short8*>(
                    sm + (qi * 16 + lc) * LDA + ks * 32 + lr * 8);
            #pragma unroll
            for (int di = 0; di < 4; ++di)
                bv[di] = *reinterpret_cast<const short8*>(
                    vt + (size_t)bh * (HD * TSZ) + (size_t)(di * 16 + lc) * TSZ
                       + kv0 + ks * 32 + lr * 8);
            #pragma unroll
            for (int qi = 0; qi < 2; ++qi)
                #pragma unroll
                for (int di = 0; di < 4; ++di)
                    y[qi][di] = __builtin_amdgcn_mfma_f32_16x16x32_bf16(
                        as[qi], bv[di], y[qi][di], 0, 0, 0);
        }
    }

    #pragma unroll
    for (int qi = 0; qi < 2; ++qi)
        #pragma unroll
        for (int di = 0; di < 4; ++di)
            #pragma unroll
            for (int r = 0; r < 4; ++r) {
                int t = qrow0 + qi * 16 + lr * 4 + r;
                int d = di * 16 + lc;
                out[((size_t)b * TSZ + t) * CSZ + h * HD + d] = y[qi][di][r];
            }
}

extern "C" void kernel_launch(void* const* d_in, const int* in_sizes, int n_in,
                              void* d_out, int out_size, void* d_ws, size_t ws_size,
                              hipStream_t stream) {
    const float* x    = (const float*)d_in[0];
    const float* W    = (const float*)d_in[1];
    const float* bias = (const float*)d_in[2];
    float* out = (float*)d_out;

    unsigned short* qo  = (unsigned short*)d_ws;                 // 96*1024*64
    unsigned short* ko  = qo + (size_t)MSZ * CSZ;
    unsigned short* vto = ko + (size_t)MSZ * CSZ;

    qkv_gemm<<<dim3(N3 / 128, MSZ / 128), 256, 0, stream>>>(x, W, bias, qo, ko, vto);
    attn_kernel<<<dim3(16, BSZ * N_HEADS), 128, 0, stream>>>(qo, ko, vto, out);
}

// Round 9
// 138.482 us; speedup vs baseline: 2.8891x; 2.8891x over previous
//
#include <hip/hip_runtime.h>
#include <hip/hip_bf16.h>
#include <stdint.h>

typedef __attribute__((ext_vector_type(8))) short short8;
typedef __attribute__((ext_vector_type(4))) float f32x4;

#define N_HEADS 12
#define HD      64
#define BSZ     8
#define TSZ     1024
#define CSZ     768
#define MSZ     (BSZ * TSZ)   /* 8192 */
#define N3      (3 * CSZ)     /* 2304 */
#define LDA     72            /* padded LDS stride for attn S-tile */

static __device__ __forceinline__ unsigned short f2bf(float f) {
    union { float f; uint32_t u; } v; v.f = f;
    uint32_t r = v.u + 0x7fffu + ((v.u >> 16) & 1u);
    return (unsigned short)(r >> 16);
}

// pack 8 consecutive f32 (two float4) into a bf16x8 fragment (RNE)
static __device__ __forceinline__ short8 pack8(float4 a, float4 b) {
    union { short8 s; __hip_bfloat162 h[4]; } u;
    u.h[0] = __float22bfloat162_rn(make_float2(a.x, a.y));
    u.h[1] = __float22bfloat162_rn(make_float2(a.z, a.w));
    u.h[2] = __float22bfloat162_rn(make_float2(b.x, b.y));
    u.h[3] = __float22bfloat162_rn(make_float2(b.z, b.w));
    return u.s;
}

// ---------------- QKV projection GEMM (fused-cvt staging, swizzled LDS) ----
// C[m][n] = sum_k x[m][k]*W[n][k] + b[n]. f32 loaded to regs, converted to
// bf16 at ds_write time (no separate cvt pass, no extra HBM round trip).
// LDS tile [128][64] bf16 with XOR column swizzle c8 ^= (row&7): both write
// and read apply the same involution -> conflict-free b128 (r7-verified).
__global__ __launch_bounds__(256, 2) void qkv_gemm(
    const float* __restrict__ x,    // [8192][768] f32
    const float* __restrict__ W,    // [2304][768] f32
    const float* __restrict__ bias, // [2304] f32
    unsigned short* __restrict__ qo,
    unsigned short* __restrict__ ko,
    unsigned short* __restrict__ vto)
{
    __shared__ unsigned short At[128 * 64];
    __shared__ unsigned short Bt[128 * 64];
    const int tid = threadIdx.x;
    const int lane = tid & 63;
    const int w = tid >> 6;
    const int lr = lane >> 4, lc = lane & 15;
    const int m0 = blockIdx.y * 128;
    const int n0 = blockIdx.x * 128;
    const int wm = (w >> 1) * 64, wn = (w & 1) * 64;

    f32x4 acc[4][4] = {};

    for (int kt = 0; kt < CSZ; kt += 64) {
        // ---- stage: 4 segments of 8 f32 each for A and B per thread ----
        float4 ra[4][2], rb[4][2];
        #pragma unroll
        for (int j = 0; j < 4; ++j) {
            int s = j * 256 + tid;           // 0..1023
            int row = s >> 3, c8 = s & 7;
            const float* pa = x + (size_t)(m0 + row) * CSZ + kt + c8 * 8;
            const float* pb = W + (size_t)(n0 + row) * CSZ + kt + c8 * 8;
            ra[j][0] = *reinterpret_cast<const float4*>(pa);
            ra[j][1] = *reinterpret_cast<const float4*>(pa + 4);
            rb[j][0] = *reinterpret_cast<const float4*>(pb);
            rb[j][1] = *reinterpret_cast<const float4*>(pb + 4);
        }
        __syncthreads();                     // previous tile's readers done
        #pragma unroll
        for (int j = 0; j < 4; ++j) {
            int s = j * 256 + tid;
            int row = s >> 3, c8 = s & 7;
            int off = row * 64 + ((c8 ^ (row & 7)) * 8);   // swizzled
            *reinterpret_cast<short8*>(At + off) = pack8(ra[j][0], ra[j][1]);
            *reinterpret_cast<short8*>(Bt + off) = pack8(rb[j][0], rb[j][1]);
        }
        __syncthreads();
        // ---- compute ----
        #pragma unroll
        for (int ks = 0; ks < 2; ++ks) {
            short8 af[4], bf_[4];
            #pragma unroll
            for (int mi = 0; mi < 4; ++mi)
                af[mi] = *reinterpret_cast<const short8*>(
                    At + (wm + mi * 16 + lc) * 64 + (((ks * 4 + lr) ^ (lc & 7)) * 8));
            #pragma unroll
            for (int ni = 0; ni < 4; ++ni)
                bf_[ni] = *reinterpret_cast<const short8*>(
                    Bt + (wn + ni * 16 + lc) * 64 + (((ks * 4 + lr) ^ (lc & 7)) * 8));
            #pragma unroll
            for (int mi = 0; mi < 4; ++mi)
                #pragma unroll
                for (int ni = 0; ni < 4; ++ni)
                    acc[mi][ni] = __builtin_amdgcn_mfma_f32_16x16x32_bf16(
                        af[mi], bf_[ni], acc[mi][ni], 0, 0, 0);
        }
    }

    // 768 is a multiple of 128, so the q/k/v section is uniform per block.
    const int sec = n0 / CSZ;
    const int nb = n0 - sec * CSZ;
    #pragma unroll
    for (int ni = 0; ni < 4; ++ni) {
        int ncol = wn + ni * 16 + lc;       // 0..127 within block
        int nn = nb + ncol;                 // 0..767 within section
        float badd = bias[n0 + ncol];
        int h = nn >> 6, d = nn & 63;
        #pragma unroll
        for (int mi = 0; mi < 4; ++mi) {
            #pragma unroll
            for (int r = 0; r < 4; ++r) {
                int m = m0 + wm + mi * 16 + lr * 4 + r;
                int bb = m >> 10, t = m & 1023;
                int plane = bb * N_HEADS + h;
                float v = acc[mi][ni][r] + badd;
                if (sec == 0)
                    qo[((size_t)plane * TSZ + t) * HD + d] = f2bf(v * 0.125f);
                else if (sec == 1)
                    ko[((size_t)plane * TSZ + t) * HD + d] = f2bf(v);
                else
                    vto[((size_t)plane * HD + d) * TSZ + t] = f2bf(v);
            }
        }
    }
}

// ---------------- causal-ReLU attention (XCD-locality swizzled) ----------
// 1536 blocks, 1D grid. Dispatch round-robins blockIdx over 8 XCDs, so we
// map: xcd = bid&7 gets bh in [xcd*12, xcd*12+12) -> each XCD reads only
// its 12 heads' K/V/Q (3 MB working set, L2-fit) instead of all 96.
// 2 waves per block: wave 0 -> q-tile qt, wave 1 -> q-tile 31-qt (every
// block runs exactly 17 kv-steps). Waves independent, no block sync.
__global__ __launch_bounds__(128, 3) void attn_kernel(
    const unsigned short* __restrict__ q,    // [96][1024][64] bf16 (pre-scaled)
    const unsigned short* __restrict__ k,    // [96][1024][64] bf16
    const unsigned short* __restrict__ vt,   // [96][64][1024] bf16
    float* __restrict__ out)                 // [8][1024][768] f32
{
    __shared__ unsigned short smem[2 * 32 * LDA];
    const int wid = threadIdx.x >> 6;
    const int lane = threadIdx.x & 63;
    const int lr = lane >> 4, lc = lane & 15;
    const int xcd = blockIdx.x & 7, slot = blockIdx.x >> 3;   // slot 0..191
    const int bh = xcd * 12 + (slot >> 4);   // 0..95, 12 heads per XCD
    const int qt = slot & 15;
    const int qw = wid == 0 ? qt : 31 - qt;  // 0..31
    const int b = bh / N_HEADS, h = bh - b * N_HEADS;
    const size_t base = (size_t)bh * (TSZ * HD);
    const int qrow0 = qw * 32;
    const int lastkt = qw >> 1;
    unsigned short* sm = smem + wid * 32 * LDA;

    // Q fragments (MFMA B operand for the S^T trick): 2 q-frags x 2 k-slices
    short8 aq[2][2];
    #pragma unroll
    for (int ks = 0; ks < 2; ++ks)
        #pragma unroll
        for (int qi = 0; qi < 2; ++qi)
            aq[ks][qi] = *reinterpret_cast<const short8*>(
                q + base + (size_t)(qrow0 + qi * 16 + lc) * HD + ks * 32 + lr * 8);

    f32x4 y[2][4] = {};

    for (int kt = 0; kt <= lastkt; ++kt) {
        const int kv0 = kt * 64;
        f32x4 st[4][2] = {};   // S^T fragments: rows kv (4x16), cols q (2x16)
        #pragma unroll
        for (int ks = 0; ks < 2; ++ks) {
            short8 ak[4];
            #pragma unroll
            for (int ki = 0; ki < 4; ++ki)
                ak[ki] = *reinterpret_cast<const short8*>(
                    k + base + (size_t)(kv0 + ki * 16 + lc) * HD + ks * 32 + lr * 8);
            #pragma unroll
            for (int ki = 0; ki < 4; ++ki)
                #pragma unroll
                for (int qi = 0; qi < 2; ++qi)
                    st[ki][qi] = __builtin_amdgcn_mfma_f32_16x16x32_bf16(
                        ak[ki], aq[ks][qi], st[ki][qi], 0, 0, 0);
        }
        const bool diag = (kt == lastkt);
        #pragma unroll
        for (int ki = 0; ki < 4; ++ki) {
            #pragma unroll
            for (int qi = 0; qi < 2; ++qi) {
                float vv[4];
                #pragma unroll
                for (int r = 0; r < 4; ++r) {
                    float s = fmaxf(st[ki][qi][r], 0.0f);          // ReLU
                    if (diag && (kv0 + ki * 16 + lr * 4 + r > qrow0 + qi * 16 + lc))
                        s = 0.0f;                                   // causal mask
                    vv[r] = s;
                }
                __hip_bfloat162 p0 = __float22bfloat162_rn(make_float2(vv[0], vv[1]));
                __hip_bfloat162 p1 = __float22bfloat162_rn(make_float2(vv[2], vv[3]));
                uint2 pk;
                pk.x = *reinterpret_cast<unsigned*>(&p0);
                pk.y = *reinterpret_cast<unsigned*>(&p1);
                // S[q][kv] layout: 4 consecutive kv per lane -> one b64 write
                *reinterpret_cast<uint2*>(
                    sm + (qi * 16 + lc) * LDA + ki * 16 + lr * 4) = pk;
            }
        }
        // PV: y[q][d] += S[q][kv] * V[kv][d]  (V via transposed vt[d][kv])
        #pragma unroll
        for (int ks = 0; ks < 2; ++ks) {
            short8 as[2], bv[4];
            #pragma unroll
            for (int qi = 0; qi < 2; ++qi)
                as[qi] = *reinterpret_cast<const short8*>(
                    sm + (qi * 16 + lc) * LDA + ks * 32 + lr * 8);
            #pragma unroll
            for (int di = 0; di < 4; ++di)
                bv[di] = *reinterpret_cast<const short8*>(
                    vt + (size_t)bh * (HD * TSZ) + (size_t)(di * 16 + lc) * TSZ
                       + kv0 + ks * 32 + lr * 8);
            #pragma unroll
            for (int qi = 0; qi < 2; ++qi)
                #pragma unroll
                for (int di = 0; di < 4; ++di)
                    y[qi][di] = __builtin_amdgcn_mfma_f32_16x16x32_bf16(
                        as[qi], bv[di], y[qi][di], 0, 0, 0);
        }
    }

    #pragma unroll
    for (int qi = 0; qi < 2; ++qi)
        #pragma unroll
        for (int di = 0; di < 4; ++di)
            #pragma unroll
            for (int r = 0; r < 4; ++r) {
                int t = qrow0 + qi * 16 + lr * 4 + r;
                int d = di * 16 + lc;
                out[((size_t)b * TSZ + t) * CSZ + h * HD + d] = y[qi][di][r];
            }
}

extern "C" void kernel_launch(void* const* d_in, const int* in_sizes, int n_in,
                              void* d_out, int out_size, void* d_ws, size_t ws_size,
                              hipStream_t stream) {
    const float* x    = (const float*)d_in[0];
    const float* W    = (const float*)d_in[1];
    const float* bias = (const float*)d_in[2];
    float* out = (float*)d_out;

    unsigned short* qo  = (unsigned short*)d_ws;                 // 96*1024*64
    unsigned short* ko  = qo + (size_t)MSZ * CSZ;
    unsigned short* vto = ko + (size_t)MSZ * CSZ;

    qkv_gemm<<<dim3(N3 / 128, MSZ / 128), 256, 0, stream>>>(x, W, bias, qo, ko, vto);
    attn_kernel<<<dim3(1536), 128, 0, stream>>>(qo, ko, vto, out);
}